// Round 1
// baseline (2401.308 us; speedup 1.0000x reference)
//
#include <hip/hip_runtime.h>
#include <math.h>

// Quantized ConvBlock: x[16,128,128,128] f32, W[256,128,3,3] f32, b[256] f32
// -> relu(conv(round(fx*x), round(fw[o]*W)) / (fx*fw[o]) + b[o]), out [16,256,128,128] f32
//
// Constants (computed in double, baked):
//   factor = sqrt(2^24) = 4096
//   sf = sqrt(48/1152) = 0.20412414523193148
//   FW_NUM = factor/sf - sqrt(1152/12)*5 = 20017.23017802413
//   FX_NUM = factor*sf - 0.5           = 835.5924988699913
//
// ws layout (floats): [0] = xmax bits (uint, memset to 0 first)
//                     [64..319]  = fw[256]
//                     [512..]    = Wq transposed [c][tap][o] : 128*9*256 floats

#define FW_NUM 20017.23017802413f
#define FX_NUM 835.5924988699913f
#define CC 8

__global__ void xmax_kernel(const float* __restrict__ x, unsigned int* wsu, int n4) {
    int tid = blockIdx.x * blockDim.x + threadIdx.x;
    int stride = gridDim.x * blockDim.x;
    const float4* x4 = (const float4*)x;
    float m = 0.f;
    for (int i = tid; i < n4; i += stride) {
        float4 v = x4[i];
        m = fmaxf(m, fmaxf(fmaxf(fabsf(v.x), fabsf(v.y)), fmaxf(fabsf(v.z), fabsf(v.w))));
    }
    #pragma unroll
    for (int off = 32; off >= 1; off >>= 1)
        m = fmaxf(m, __shfl_down(m, off, 64));
    __shared__ float sm[4];
    if ((threadIdx.x & 63) == 0) sm[threadIdx.x >> 6] = m;
    __syncthreads();
    if (threadIdx.x == 0) {
        m = fmaxf(fmaxf(sm[0], sm[1]), fmaxf(sm[2], sm[3]));
        atomicMax(wsu, __float_as_uint(m));   // nonneg floats: uint order == float order
    }
}

// one block per output channel o (256 blocks, 128 threads; thread t = input channel c)
__global__ void wq_kernel(const float* __restrict__ W, float* wsf) {
    int o = blockIdx.x;
    int t = threadIdx.x;
    const float* wrow = W + o * 1152;
    float wv[9];
    float s = 0.f;
    #pragma unroll
    for (int k = 0; k < 9; k++) { wv[k] = wrow[t * 9 + k]; s += fabsf(wv[k]); }
    #pragma unroll
    for (int off = 32; off >= 1; off >>= 1) s += __shfl_down(s, off, 64);
    __shared__ float sred[2];
    __shared__ float sfw;
    if ((t & 63) == 0) sred[t >> 6] = s;
    __syncthreads();
    if (t == 0) {
        float wsum = sred[0] + sred[1];
        if (wsum == 0.f) wsum = 1.f;
        float fw = FW_NUM / wsum;
        wsf[64 + o] = fw;
        sfw = fw;
    }
    __syncthreads();
    float fw = sfw;
    float* wqt = wsf + 512;
    #pragma unroll
    for (int k = 0; k < 9; k++) {
        // Wq transposed: [c][tap][o]; rintf = round-half-to-even, matches jnp.round
        wqt[(t * 9 + k) * 256 + o] = rintf(wv[k] * fw);
    }
}

// block: 32 out-ch x 2 rows x 128 w. thread: 8 o x 4 w micro-tile. c-chunks of 8.
__global__ __launch_bounds__(256) void conv_kernel(const float* __restrict__ x,
                                                   const float* __restrict__ b,
                                                   const float* __restrict__ wsf,
                                                   float* __restrict__ out) {
    __shared__ __align__(16) float xs[CC][4][132];   // rows h0-1..h0+2, w index j -> w=j-1
    __shared__ __align__(16) float wlds[CC][9][32];

    const unsigned int* wsu = (const unsigned int*)wsf;
    float xmax = __uint_as_float(wsu[0]);
    float fx = xmax > 0.f ? FX_NUM / xmax : 1.0f;

    int bx = blockIdx.x;               // 1024 = 16 n * 64 h-pairs
    int n  = bx >> 6;
    int h0 = (bx & 63) << 1;
    int o0 = blockIdx.y << 5;          // 8 tiles of 32 channels

    int tid = threadIdx.x;
    int wz = tid & 31;                 // w-tile of 4
    int hz = (tid >> 5) & 1;           // row within pair
    int oz = tid >> 6;                 // o-group of 8 (wave-uniform!)

    const float* wqt = wsf + 512;
    const float* xn = x + n * (128 * 128 * 128);

    float acc[8][4];
    #pragma unroll
    for (int i = 0; i < 8; i++)
        #pragma unroll
        for (int j = 0; j < 4; j++) acc[i][j] = 0.f;

    for (int c0 = 0; c0 < 128; c0 += CC) {
        __syncthreads();
        // stage x (quantize on load): CC*4*132 = 4224 elements
        for (int idx = tid; idx < CC * 4 * 132; idx += 256) {
            int c = idx / 528;
            int rem = idx - c * 528;
            int r = rem / 132;
            int j = rem - r * 132;
            int h = h0 + r - 1;
            int w = j - 1;
            float v = 0.f;
            if (h >= 0 && h < 128 && w >= 0 && w < 128)
                v = rintf(fx * xn[(c0 + c) * 16384 + h * 128 + w]);
            xs[c][r][j] = v;
        }
        // stage Wq: CC*9*32 = 2304 elements
        for (int idx = tid; idx < CC * 9 * 32; idx += 256) {
            int c = idx / 288;
            int rem = idx - c * 288;
            int tap = rem / 32;
            int oo = rem - tap * 32;
            wlds[c][tap][oo] = wqt[((c0 + c) * 9 + tap) * 256 + o0 + oo];
        }
        __syncthreads();

        for (int c = 0; c < CC; c++) {
            #pragma unroll
            for (int kh = 0; kh < 3; kh++) {
                const float* xrow = &xs[c][hz + kh][wz * 4];
                float x6[6];
                #pragma unroll
                for (int q = 0; q < 6; q++) x6[q] = xrow[q];
                #pragma unroll
                for (int kw = 0; kw < 3; kw++) {
                    const float* wp = &wlds[c][kh * 3 + kw][oz * 8];  // wave-uniform: broadcast
                    #pragma unroll
                    for (int i = 0; i < 8; i++) {
                        float wv = wp[i];
                        #pragma unroll
                        for (int j = 0; j < 4; j++)
                            acc[i][j] = fmaf(wv, x6[kw + j], acc[i][j]);
                    }
                }
            }
        }
    }

    // epilogue: dequant + bias + relu
    int h = h0 + hz;
    float* outp = out + ((size_t)(n * 256 + o0 + oz * 8) * 128 + h) * 128 + wz * 4;
    #pragma unroll
    for (int i = 0; i < 8; i++) {
        float fw = wsf[64 + o0 + oz * 8 + i];
        float scale = 1.0f / (fx * fw);
        float bias = b[o0 + oz * 8 + i];
        float4 r;
        r.x = fmaxf(fmaf(acc[i][0], scale, bias), 0.f);
        r.y = fmaxf(fmaf(acc[i][1], scale, bias), 0.f);
        r.z = fmaxf(fmaf(acc[i][2], scale, bias), 0.f);
        r.w = fmaxf(fmaf(acc[i][3], scale, bias), 0.f);
        *(float4*)(outp + (size_t)i * 16384) = r;
    }
}

extern "C" void kernel_launch(void* const* d_in, const int* in_sizes, int n_in,
                              void* d_out, int out_size, void* d_ws, size_t ws_size,
                              hipStream_t stream) {
    const float* x = (const float*)d_in[0];   // [16,128,128,128]
    const float* W = (const float*)d_in[1];   // [256,128,3,3]
    const float* b = (const float*)d_in[2];   // [256]
    float* out = (float*)d_out;
    float* wsf = (float*)d_ws;

    // zero the xmax slot (ws is poisoned 0xAA each call)
    hipMemsetAsync(d_ws, 0, 256, stream);

    xmax_kernel<<<1024, 256, 0, stream>>>(x, (unsigned int*)d_ws, (16 * 128 * 128 * 128) / 4);
    wq_kernel<<<256, 128, 0, stream>>>(W, wsf);

    dim3 grid(1024, 8);
    conv_kernel<<<grid, 256, 0, stream>>>(x, b, wsf, out);
}

// Round 2
// 665.420 us; speedup vs baseline: 3.6087x; 3.6087x over previous
//
#include <hip/hip_runtime.h>
#include <math.h>

// Quantized ConvBlock via implicit-GEMM MFMA (fp16 inputs, fp32 accum):
//   xq = rint(fx*x) integers <= 836 (exact in f16), wq integers <= ~100 (exact in f16)
// GEMM: M = n*h*w pixels, N = 256 out-ch, K = 128 in-ch x 9 taps.
// Block: M512 (4 rows x 128 w) x N64; 4 waves, wave tile 128x64 = 4x2 mfma_32x32x16.
//
// Constants: factor=4096, sf=sqrt(48/1152); FW_NUM = factor/sf - sqrt(1152/12)*5
//            FX_NUM = factor*sf - 0.5
// ws: [0]=xmax bits; [64..319]=fw[256]; (f16*)(wsf+512) = Wq [o][tap][c] 256*9*128

#define FW_NUM 20017.23017802413f
#define FX_NUM 835.5924988699913f
#define CK  16
#define CKP 24      // pad 16->24: keeps 16B alignment of 8-half frags; 12-dword lane stride
#define JW  130     // w index j = w+1, j in 0..129 (halo j=0, j=129)

typedef _Float16 half8 __attribute__((ext_vector_type(8)));
typedef _Float16 half4 __attribute__((ext_vector_type(4)));
typedef float floatx16 __attribute__((ext_vector_type(16)));

__global__ void xmax_kernel(const float* __restrict__ x, unsigned int* wsu, int n4) {
    int tid = blockIdx.x * blockDim.x + threadIdx.x;
    int stride = gridDim.x * blockDim.x;
    const float4* x4 = (const float4*)x;
    float m = 0.f;
    for (int i = tid; i < n4; i += stride) {
        float4 v = x4[i];
        m = fmaxf(m, fmaxf(fmaxf(fabsf(v.x), fabsf(v.y)), fmaxf(fabsf(v.z), fabsf(v.w))));
    }
    #pragma unroll
    for (int off = 32; off >= 1; off >>= 1)
        m = fmaxf(m, __shfl_down(m, off, 64));
    __shared__ float sm[4];
    if ((threadIdx.x & 63) == 0) sm[threadIdx.x >> 6] = m;
    __syncthreads();
    if (threadIdx.x == 0) {
        m = fmaxf(fmaxf(sm[0], sm[1]), fmaxf(sm[2], sm[3]));
        atomicMax(wsu, __float_as_uint(m));
    }
}

// one block per o (256 blocks, 128 threads; t = input channel c)
__global__ void wq_kernel(const float* __restrict__ W, float* wsf) {
    int o = blockIdx.x;
    int t = threadIdx.x;
    const float* wrow = W + o * 1152;
    float wv[9];
    float s = 0.f;
    #pragma unroll
    for (int k = 0; k < 9; k++) { wv[k] = wrow[t * 9 + k]; s += fabsf(wv[k]); }
    #pragma unroll
    for (int off = 32; off >= 1; off >>= 1) s += __shfl_down(s, off, 64);
    __shared__ float sred[2];
    __shared__ float sfw;
    if ((t & 63) == 0) sred[t >> 6] = s;
    __syncthreads();
    if (t == 0) {
        float wsum = sred[0] + sred[1];
        if (wsum == 0.f) wsum = 1.f;
        float fw = FW_NUM / wsum;
        wsf[64 + o] = fw;
        sfw = fw;
    }
    __syncthreads();
    float fw = sfw;
    _Float16* wq16 = (_Float16*)(wsf + 512);   // layout [o][tap][c]
    #pragma unroll
    for (int k = 0; k < 9; k++)
        wq16[(o * 9 + k) * 128 + t] = (_Float16)rintf(wv[k] * fw);
}

__global__ __launch_bounds__(256, 2) void conv_kernel(const float* __restrict__ x,
                                                      const float* __restrict__ bias,
                                                      const float* __restrict__ wsf,
                                                      float* __restrict__ out) {
    __shared__ __align__(16) _Float16 xs[6 * JW * CKP];    // 37440 B
    __shared__ __align__(16) _Float16 wlds[9 * 64 * CKP];  // 27648 B

    const unsigned int* wsu = (const unsigned int*)wsf;
    float xmax = __uint_as_float(wsu[0]);
    float fx = xmax > 0.f ? FX_NUM / xmax : 1.0f;

    int bx = blockIdx.x;              // 512 = 16 n * 32 h-quads
    int n  = bx >> 5;
    int h0 = (bx & 31) << 2;
    int o0 = blockIdx.y << 6;         // 4 tiles of 64 o

    int tid  = threadIdx.x;
    int lane = tid & 63;
    int wave = tid >> 6;              // wave handles output row h0+wave
    int m32  = lane & 31;
    int q2   = lane >> 5;             // k-half selector

    const _Float16* wq16 = (const _Float16*)(wsf + 512);
    const float* xn = x + (size_t)n * (128 * 128 * 128);

    floatx16 acc[4][2];
    #pragma unroll
    for (int mt = 0; mt < 4; mt++)
        #pragma unroll
        for (int nt = 0; nt < 2; nt++)
            #pragma unroll
            for (int e = 0; e < 16; e++) acc[mt][nt][e] = 0.f;

    // zero the w-halo (j=0 and j=129) once; only c 0..15 are ever read
    if (tid < 192) {
        int r = tid >> 5;
        int s = tid & 31;
        int c = s & 15;
        int j = (s >> 4) ? (JW - 1) : 0;
        xs[(r * JW + j) * CKP + c] = (_Float16)0.f;
    }

    for (int c0 = 0; c0 < 128; c0 += CK) {
        __syncthreads();
        // ---- stage x: 6 rows x 128 w x 16 c; lane-per-w (coalesced global, clean LDS banks)
        #pragma unroll
        for (int it = 0; it < 12; ++it) {
            int idx = tid + it * 256;        // 3072 tasks
            int j  = (idx & 127) + 1;        // w = j-1
            int c4 = (idx >> 7) & 3;
            int r  = idx >> 9;               // 0..5
            int h  = h0 + r - 1;
            float v0 = 0.f, v1 = 0.f, v2 = 0.f, v3 = 0.f;
            if (h >= 0 && h < 128) {
                const float* xp = xn + (size_t)(c0 + c4 * 4) * 16384 + h * 128 + (j - 1);
                v0 = xp[0]; v1 = xp[16384]; v2 = xp[32768]; v3 = xp[49152];
            }
            half4 hv;
            hv[0] = (_Float16)rintf(fx * v0);
            hv[1] = (_Float16)rintf(fx * v1);
            hv[2] = (_Float16)rintf(fx * v2);
            hv[3] = (_Float16)rintf(fx * v3);
            *(half4*)&xs[(r * JW + j) * CKP + c4 * 4] = hv;
        }
        // ---- stage Wq: 9 taps x 64 o x 16 c as b128
        #pragma unroll
        for (int it = 0; it < 5; ++it) {
            int idx = tid + it * 256;        // 1152 tasks
            if (idx < 1152) {
                int o   = idx / 18;
                int rem = idx - o * 18;
                int tap = rem >> 1;
                int g   = rem & 1;
                half8 v = *(const half8*)(wq16 + ((size_t)(o0 + o) * 9 + tap) * 128 + c0 + g * 8);
                *(half8*)&wlds[(tap * 64 + o) * CKP + g * 8] = v;
            }
        }
        __syncthreads();

        // ---- MFMA over 9 taps
        const _Float16* xbase = &xs[(wave * JW + m32) * CKP + q2 * 8];
        const _Float16* wbase = &wlds[m32 * CKP + q2 * 8];
        #pragma unroll
        for (int kh = 0; kh < 3; ++kh) {
            #pragma unroll
            for (int kw = 0; kw < 3; ++kw) {
                int tap = kh * 3 + kw;
                half8 b0 = *(const half8*)(wbase + (tap * 64 +  0) * CKP);
                half8 b1 = *(const half8*)(wbase + (tap * 64 + 32) * CKP);
                #pragma unroll
                for (int mt = 0; mt < 4; ++mt) {
                    half8 a = *(const half8*)(xbase + (kh * JW + kw + mt * 32) * CKP);
                    acc[mt][0] = __builtin_amdgcn_mfma_f32_32x32x16_f16(a, b0, acc[mt][0], 0, 0, 0);
                    acc[mt][1] = __builtin_amdgcn_mfma_f32_32x32x16_f16(a, b1, acc[mt][1], 0, 0, 0);
                }
            }
        }
    }

    // ---- epilogue: D[m][n]: n = lane&31 (o), m = (reg&3) + 8*(reg>>2) + 4*q2 (w)
    int h = h0 + wave;
    #pragma unroll
    for (int nt = 0; nt < 2; ++nt) {
        int o = o0 + nt * 32 + m32;
        float fwv = wsf[64 + o];
        float scale = 1.0f / (fx * fwv);
        float bv = bias[o];
        float* op = out + (((size_t)n * 256 + o) * 128 + h) * 128;
        #pragma unroll
        for (int mt = 0; mt < 4; ++mt) {
            #pragma unroll
            for (int g = 0; g < 4; ++g) {
                int w = mt * 32 + 8 * g + 4 * q2;
                float4 r;
                r.x = fmaxf(fmaf(acc[mt][nt][4 * g + 0], scale, bv), 0.f);
                r.y = fmaxf(fmaf(acc[mt][nt][4 * g + 1], scale, bv), 0.f);
                r.z = fmaxf(fmaf(acc[mt][nt][4 * g + 2], scale, bv), 0.f);
                r.w = fmaxf(fmaf(acc[mt][nt][4 * g + 3], scale, bv), 0.f);
                *(float4*)(op + w) = r;
            }
        }
    }
}

extern "C" void kernel_launch(void* const* d_in, const int* in_sizes, int n_in,
                              void* d_out, int out_size, void* d_ws, size_t ws_size,
                              hipStream_t stream) {
    const float* x = (const float*)d_in[0];   // [16,128,128,128]
    const float* W = (const float*)d_in[1];   // [256,128,3,3]
    const float* b = (const float*)d_in[2];   // [256]
    float* out = (float*)d_out;
    float* wsf = (float*)d_ws;

    hipMemsetAsync(d_ws, 0, 256, stream);     // xmax slot (ws poisoned 0xAA)

    xmax_kernel<<<1024, 256, 0, stream>>>(x, (unsigned int*)d_ws, (16 * 128 * 128 * 128) / 4);
    wq_kernel<<<256, 128, 0, stream>>>(W, wsf);

    dim3 grid(512, 4);                        // 16 n * 32 h-quads, 4 o-tiles
    conv_kernel<<<grid, 256, 0, stream>>>(x, b, wsf, out);
}

// Round 3
// 504.951 us; speedup vs baseline: 4.7555x; 1.3178x over previous
//
#include <hip/hip_runtime.h>
#include <math.h>

// Quantized ConvBlock, round 3: async-pipelined implicit-GEMM MFMA.
//   Pass 1: xmax reduction.  Pass 2: xq = f16(rint(fx*x)) in layout [n][cc][h][w][c16].
//   Pass 3: conv; A = Wq (M=o), B = xq (N=pixels), K = 16c per chunk x 9 taps x 8 chunks.
//   Block: 64 o x (8 rows x 64 w); 4 waves; wave = 64 o x 128 pixels = 2x4 mfma_32x32x16.
//   Double-buffered LDS, global_load_lds width-16 staging, one barrier per chunk.
//
// ws layout (bytes):
//   0        : xmax bits (uint)             [memset to 0]
//   256      : fw[256] floats
//   2048     : wq_a  f16 [o][tap][c]        (fallback layout, 589824 B)
//   655360   : wq_b  f16 [cc][tap][o][c16]  (main layout, 589824 B)
//   2097152  : xq    f16 [n][cc][h][w][c16] (67108864 B)

#define FW_NUM 20017.23017802413f
#define FX_NUM 835.5924988699913f
#define WQA_OFF 2048
#define WQB_OFF (640 * 1024)
#define XQ_OFF  (2 * 1024 * 1024)
#define XQ_BYTES 67108864ull

// fallback-kernel tile params (R2 kernel, kept verbatim)
#define CK  16
#define CKP 24
#define JW  130

typedef _Float16 half8 __attribute__((ext_vector_type(8)));
typedef _Float16 half4 __attribute__((ext_vector_type(4)));
typedef float floatx16 __attribute__((ext_vector_type(16)));

__device__ __forceinline__ void gl_lds16(const void* g, void* s) {
    __builtin_amdgcn_global_load_lds((const __attribute__((address_space(1))) void*)g,
                                     (__attribute__((address_space(3))) void*)s, 16, 0, 0);
}

__global__ void xmax_kernel(const float* __restrict__ x, unsigned int* wsu, int n4) {
    int tid = blockIdx.x * blockDim.x + threadIdx.x;
    int stride = gridDim.x * blockDim.x;
    const float4* x4 = (const float4*)x;
    float m = 0.f;
    for (int i = tid; i < n4; i += stride) {
        float4 v = x4[i];
        m = fmaxf(m, fmaxf(fmaxf(fabsf(v.x), fabsf(v.y)), fmaxf(fabsf(v.z), fabsf(v.w))));
    }
    #pragma unroll
    for (int off = 32; off >= 1; off >>= 1)
        m = fmaxf(m, __shfl_down(m, off, 64));
    __shared__ float sm[4];
    if ((threadIdx.x & 63) == 0) sm[threadIdx.x >> 6] = m;
    __syncthreads();
    if (threadIdx.x == 0) {
        m = fmaxf(fmaxf(sm[0], sm[1]), fmaxf(sm[2], sm[3]));
        atomicMax(wsu, __float_as_uint(m));
    }
}

// one block per o (256 blocks, 128 threads; t = input channel c)
__global__ void wq_kernel(const float* __restrict__ W, float* wsf, int big) {
    int o = blockIdx.x;
    int t = threadIdx.x;
    const float* wrow = W + o * 1152;
    float wv[9];
    float s = 0.f;
    #pragma unroll
    for (int k = 0; k < 9; k++) { wv[k] = wrow[t * 9 + k]; s += fabsf(wv[k]); }
    #pragma unroll
    for (int off = 32; off >= 1; off >>= 1) s += __shfl_down(s, off, 64);
    __shared__ float sred[2];
    __shared__ float sfw;
    if ((t & 63) == 0) sred[t >> 6] = s;
    __syncthreads();
    if (t == 0) {
        float wsum = sred[0] + sred[1];
        if (wsum == 0.f) wsum = 1.f;
        float fw = FW_NUM / wsum;
        wsf[64 + o] = fw;
        sfw = fw;
    }
    __syncthreads();
    float fw = sfw;
    _Float16* wqa = (_Float16*)((char*)wsf + WQA_OFF);   // [o][tap][c]
    _Float16* wqb = (_Float16*)((char*)wsf + WQB_OFF);   // [cc][tap][o][c16]
    #pragma unroll
    for (int k = 0; k < 9; k++) {
        _Float16 hv = (_Float16)rintf(wv[k] * fw);       // rintf = RNE = jnp.round
        wqa[(o * 9 + k) * 128 + t] = hv;
        if (big)
            wqb[(((t >> 4) * 9 + k) * 256 + o) * 16 + (t & 15)] = hv;
    }
}

// block = one (n, cc, h): quantize 16 c-planes' row h into [w][c16] (4 KB contiguous)
__global__ void quantx_kernel(const float* __restrict__ x, const float* __restrict__ wsf,
                              _Float16* __restrict__ xq) {
    int bid = blockIdx.x;           // (n*8 + cc)*128 + h
    int h  = bid & 127;
    int cc = (bid >> 7) & 7;
    int n  = bid >> 10;
    float xmax = __uint_as_float(((const unsigned int*)wsf)[0]);
    float fx = xmax > 0.f ? FX_NUM / xmax : 1.0f;
    int w = threadIdx.x;            // 128
    const float* xp = x + ((size_t)(n * 128 + cc * 16) * 128 + h) * 128 + w;
    half8 v0, v1;
    #pragma unroll
    for (int ci = 0; ci < 8; ci++)  v0[ci] = (_Float16)rintf(fx * xp[(size_t)ci * 16384]);
    #pragma unroll
    for (int ci = 8; ci < 16; ci++) v1[ci - 8] = (_Float16)rintf(fx * xp[(size_t)ci * 16384]);
    _Float16* op = xq + ((size_t)bid * 128 + w) * 16;
    *(half8*)op = v0;
    *(half8*)(op + 8) = v1;
}

__global__ __launch_bounds__(256, 2) void conv_main(const _Float16* __restrict__ xq,
                                                    const float* __restrict__ bias,
                                                    const float* __restrict__ wsf,
                                                    float* __restrict__ out) {
    // xs rows: r in 0..9 -> h = h0 + r - 1;  j in 0..65 -> w = w0 + j - 1
    __shared__ __align__(16) _Float16 xs[2][10 * 66 * 16];   // 42240 B
    __shared__ __align__(16) _Float16 wl[2][9 * 64 * 16];    // 36864 B  [tap][o][c16]
    __shared__ float sc[64], bz[64];                          // 512 B   (total 79616 B -> 2 blk/CU)

    float xmax = __uint_as_float(((const unsigned int*)wsf)[0]);
    float fx = xmax > 0.f ? FX_NUM / xmax : 1.0f;

    int bx = blockIdx.x;
    int o0 = (bx & 3) << 6;
    int w0 = ((bx >> 2) & 1) << 6;
    int h0 = ((bx >> 3) & 15) << 3;
    int n  = bx >> 7;

    int tid = threadIdx.x;
    int lane = tid & 63;
    int wv = tid >> 6;
    int m32 = lane & 31;
    int q2 = lane >> 5;

    const char* wqb = (const char*)wsf + WQB_OFF;

    // ---- init: zero both xs buffers (halo/OOB default), scale/bias to LDS
    {
        uint4 z = {0u, 0u, 0u, 0u};
        uint4* p = (uint4*)xs;
        for (int i = tid; i < (int)(sizeof(xs) / 16); i += 256) p[i] = z;
        if (tid < 64) {
            float fwv = wsf[64 + o0 + tid];
            sc[tid] = 1.0f / (fx * fwv);
            bz[tid] = bias[o0 + tid];
        }
    }
    __syncthreads();   // zero-fill visible before async writes land

    floatx16 acc[2][4];
    #pragma unroll
    for (int a1 = 0; a1 < 2; a1++)
        #pragma unroll
        for (int a2 = 0; a2 < 4; a2++)
            #pragma unroll
            for (int e = 0; e < 16; e++) acc[a1][a2][e] = 0.f;

    // ---- staging helpers
    auto stage_async = [&](int ccs, int tb) {
        // 20 x-segs (10 rows x 2 KB) + 18 w-segs (9 taps x 2 KB), 1 KB per wave-inst
        for (int s = wv; s < 38; s += 4) {
            if (s < 20) {
                int r = s >> 1, hseg = s & 1;
                int h = h0 + r - 1;
                if (h >= 0 && h < 128) {
                    size_t pix = ((size_t)((n * 8 + ccs) * 128 + h)) * 128 + w0;
                    const char* src = (const char*)xq + pix * 32 + hseg * 1024 + (size_t)lane * 16;
                    char* dst = (char*)&xs[tb][(r * 66 + 1) * 16] + hseg * 1024;
                    gl_lds16(src, dst);
                }
            } else {
                int t2 = s - 20, tap = t2 >> 1, g = t2 & 1;
                const char* src = wqb + ((size_t)(ccs * 9 + tap) * 256 + o0) * 32 + g * 1024 + (size_t)lane * 16;
                char* dst = (char*)&wl[tb][tap * 64 * 16] + g * 1024;
                gl_lds16(src, dst);
            }
        }
    };
    auto halo_load = [&](int ccs) -> half8 {
        half8 v = {};
        if (tid < 40) {
            int r = tid >> 2, sd = (tid >> 1) & 1, g = tid & 1;
            int h = h0 + r - 1;
            int wh = sd ? (w0 + 64) : (w0 - 1);
            if (h >= 0 && h < 128 && wh >= 0 && wh < 128)
                v = *(const half8*)(xq + (((size_t)((n * 8 + ccs) * 128 + h)) * 128 + wh) * 16 + g * 8);
        }
        return v;
    };
    auto halo_store = [&](int tb, half8 v) {
        if (tid < 40) {
            int r = tid >> 2, sd = (tid >> 1) & 1, g = tid & 1;
            int h = h0 + r - 1;
            int wh = sd ? (w0 + 64) : (w0 - 1);
            if (h >= 0 && h < 128 && wh >= 0 && wh < 128)
                *(half8*)&xs[tb][(r * 66 + (sd ? 65 : 0)) * 16 + g * 8] = v;
        }
    };

    // ---- prologue: chunk 0
    {
        half8 hv = halo_load(0);
        stage_async(0, 0);
        halo_store(0, hv);
    }
    __syncthreads();   // vmcnt(0)+lgkmcnt(0) drain: chunk 0 ready in buf 0

    // ---- K loop: 8 chunks of 16 c
    for (int cc = 0; cc < 8; ++cc) {
        int cb = cc & 1;
        half8 hn = {};
        if (cc < 7) {
            hn = halo_load(cc + 1);       // global->reg early (latency hidden by MFMA)
            stage_async(cc + 1, cb ^ 1);  // async global->LDS, other buffer
        }

        // MFMA on buffer cb
        #pragma unroll
        for (int kh = 0; kh < 3; ++kh) {
            #pragma unroll
            for (int kw = 0; kw < 3; ++kw) {
                int tap = kh * 3 + kw;
                const _Float16* wp = &wl[cb][(tap * 64 + m32) * 16 + q2 * 8];
                half8 wf0 = *(const half8*)wp;
                half8 wf1 = *(const half8*)(wp + 32 * 16);
                #pragma unroll
                for (int pt = 0; pt < 4; ++pt) {
                    const _Float16* xp =
                        &xs[cb][(((wv * 2 + (pt >> 1) + kh) * 66) + (pt & 1) * 32 + m32 + kw) * 16 + q2 * 8];
                    half8 xf = *(const half8*)xp;
                    acc[0][pt] = __builtin_amdgcn_mfma_f32_32x32x16_f16(wf0, xf, acc[0][pt], 0, 0, 0);
                    acc[1][pt] = __builtin_amdgcn_mfma_f32_32x32x16_f16(wf1, xf, acc[1][pt], 0, 0, 0);
                }
            }
        }

        if (cc < 7) halo_store(cb ^ 1, hn);  // its vmcnt wait hides behind the barrier drain
        __syncthreads();
    }

    // ---- epilogue: D row = o (reg), col = pixel (lane) -> coalesced 2x128B stores
    #pragma unroll
    for (int ot = 0; ot < 2; ++ot) {
        #pragma unroll
        for (int e = 0; e < 16; ++e) {
            int o_loc = ot * 32 + (e & 3) + 8 * (e >> 2) + 4 * q2;
            float scale = sc[o_loc];
            float bv = bz[o_loc];
            #pragma unroll
            for (int pt = 0; pt < 4; ++pt) {
                int h = h0 + wv * 2 + (pt >> 1);
                int w = w0 + (pt & 1) * 32 + m32;
                float v = fmaxf(fmaf(acc[ot][pt][e], scale, bv), 0.f);
                out[(((size_t)(n * 256 + o0 + o_loc)) * 128 + h) * 128 + w] = v;
            }
        }
    }
}

// ---------------- fallback (R2 kernel, used if ws too small) ----------------
__global__ __launch_bounds__(256, 2) void conv_fallback(const float* __restrict__ x,
                                                        const float* __restrict__ bias,
                                                        const float* __restrict__ wsf,
                                                        float* __restrict__ out) {
    __shared__ __align__(16) _Float16 xs[6 * JW * CKP];
    __shared__ __align__(16) _Float16 wlds[9 * 64 * CKP];

    const unsigned int* wsu = (const unsigned int*)wsf;
    float xmax = __uint_as_float(wsu[0]);
    float fx = xmax > 0.f ? FX_NUM / xmax : 1.0f;

    int bx = blockIdx.x;
    int n  = bx >> 5;
    int h0 = (bx & 31) << 2;
    int o0 = blockIdx.y << 6;

    int tid  = threadIdx.x;
    int lane = tid & 63;
    int wave = tid >> 6;
    int m32  = lane & 31;
    int q2   = lane >> 5;

    const _Float16* wq16 = (const _Float16*)((const char*)wsf + WQA_OFF);
    const float* xn = x + (size_t)n * (128 * 128 * 128);

    floatx16 acc[4][2];
    #pragma unroll
    for (int mt = 0; mt < 4; mt++)
        #pragma unroll
        for (int nt = 0; nt < 2; nt++)
            #pragma unroll
            for (int e = 0; e < 16; e++) acc[mt][nt][e] = 0.f;

    if (tid < 192) {
        int r = tid >> 5;
        int s = tid & 31;
        int c = s & 15;
        int j = (s >> 4) ? (JW - 1) : 0;
        xs[(r * JW + j) * CKP + c] = (_Float16)0.f;
    }

    for (int c0 = 0; c0 < 128; c0 += CK) {
        __syncthreads();
        #pragma unroll
        for (int it = 0; it < 12; ++it) {
            int idx = tid + it * 256;
            int j  = (idx & 127) + 1;
            int c4 = (idx >> 7) & 3;
            int r  = idx >> 9;
            int h  = h0 + r - 1;
            float v0 = 0.f, v1 = 0.f, v2 = 0.f, v3 = 0.f;
            if (h >= 0 && h < 128) {
                const float* xp = xn + (size_t)(c0 + c4 * 4) * 16384 + h * 128 + (j - 1);
                v0 = xp[0]; v1 = xp[16384]; v2 = xp[32768]; v3 = xp[49152];
            }
            half4 hv;
            hv[0] = (_Float16)rintf(fx * v0);
            hv[1] = (_Float16)rintf(fx * v1);
            hv[2] = (_Float16)rintf(fx * v2);
            hv[3] = (_Float16)rintf(fx * v3);
            *(half4*)&xs[(r * JW + j) * CKP + c4 * 4] = hv;
        }
        #pragma unroll
        for (int it = 0; it < 5; ++it) {
            int idx = tid + it * 256;
            if (idx < 1152) {
                int o   = idx / 18;
                int rem = idx - o * 18;
                int tap = rem >> 1;
                int g   = rem & 1;
                half8 v = *(const half8*)(wq16 + ((size_t)(o0 + o) * 9 + tap) * 128 + c0 + g * 8);
                *(half8*)&wlds[(tap * 64 + o) * CKP + g * 8] = v;
            }
        }
        __syncthreads();

        const _Float16* xbase = &xs[(wave * JW + m32) * CKP + q2 * 8];
        const _Float16* wbase = &wlds[m32 * CKP + q2 * 8];
        #pragma unroll
        for (int kh = 0; kh < 3; ++kh) {
            #pragma unroll
            for (int kw = 0; kw < 3; ++kw) {
                int tap = kh * 3 + kw;
                half8 b0 = *(const half8*)(wbase + (tap * 64 +  0) * CKP);
                half8 b1 = *(const half8*)(wbase + (tap * 64 + 32) * CKP);
                #pragma unroll
                for (int mt = 0; mt < 4; ++mt) {
                    half8 a = *(const half8*)(xbase + (kh * JW + kw + mt * 32) * CKP);
                    acc[mt][0] = __builtin_amdgcn_mfma_f32_32x32x16_f16(a, b0, acc[mt][0], 0, 0, 0);
                    acc[mt][1] = __builtin_amdgcn_mfma_f32_32x32x16_f16(a, b1, acc[mt][1], 0, 0, 0);
                }
            }
        }
    }

    int h = h0 + wave;
    #pragma unroll
    for (int nt = 0; nt < 2; ++nt) {
        int o = o0 + nt * 32 + m32;
        float fwv = wsf[64 + o];
        float scale = 1.0f / (fx * fwv);
        float bv = bias[o];
        float* op = out + (((size_t)n * 256 + o) * 128 + h) * 128;
        #pragma unroll
        for (int mt = 0; mt < 4; ++mt) {
            #pragma unroll
            for (int g = 0; g < 4; ++g) {
                int w = mt * 32 + 8 * g + 4 * q2;
                float4 r;
                r.x = fmaxf(fmaf(acc[mt][nt][4 * g + 0], scale, bv), 0.f);
                r.y = fmaxf(fmaf(acc[mt][nt][4 * g + 1], scale, bv), 0.f);
                r.z = fmaxf(fmaf(acc[mt][nt][4 * g + 2], scale, bv), 0.f);
                r.w = fmaxf(fmaf(acc[mt][nt][4 * g + 3], scale, bv), 0.f);
                *(float4*)(op + w) = r;
            }
        }
    }
}

extern "C" void kernel_launch(void* const* d_in, const int* in_sizes, int n_in,
                              void* d_out, int out_size, void* d_ws, size_t ws_size,
                              hipStream_t stream) {
    const float* x = (const float*)d_in[0];   // [16,128,128,128]
    const float* W = (const float*)d_in[1];   // [256,128,3,3]
    const float* b = (const float*)d_in[2];   // [256]
    float* out = (float*)d_out;
    float* wsf = (float*)d_ws;

    int big = (ws_size >= (size_t)XQ_OFF + XQ_BYTES) ? 1 : 0;

    hipMemsetAsync(d_ws, 0, 256, stream);     // xmax slot (ws poisoned 0xAA)

    xmax_kernel<<<1024, 256, 0, stream>>>(x, (unsigned int*)d_ws, (16 * 128 * 128 * 128) / 4);
    wq_kernel<<<256, 128, 0, stream>>>(W, wsf, big);

    if (big) {
        _Float16* xq = (_Float16*)((char*)d_ws + XQ_OFF);
        quantx_kernel<<<16 * 8 * 128, 128, 0, stream>>>(x, wsf, xq);
        conv_main<<<2048, 256, 0, stream>>>(xq, b, wsf, out);
    } else {
        dim3 grid(512, 4);
        conv_fallback<<<grid, 256, 0, stream>>>(x, b, wsf, out);
    }
}